// Round 1
// 334.459 us; speedup vs baseline: 1.0454x; 1.0454x over previous
//
#include <hip/hip_runtime.h>
#include <math.h>

#define Bn 32
#define An 8732
#define Cn 201
#define Gn 50

#define APB 16                      // anchors per block in cls kernel (16 lanes/anchor, 256 thr)
#define CLS_BLOCKS ((An + APB - 1) / APB)   // 546 blocks per batch
#define LOG2E 1.44269504088896340736f

// ---------- helpers ----------
__device__ __forceinline__ unsigned int f2key(float f) {
    unsigned int u = __float_as_uint(f);
    return (u & 0x80000000u) ? ~u : (u | 0x80000000u);
}
__device__ __forceinline__ float key2f(unsigned int k) {
    return (k & 0x80000000u) ? __uint_as_float(k & 0x7FFFFFFFu) : __uint_as_float(~k);
}
__device__ __forceinline__ float smooth_l1(float d) {
    float ad = fabsf(d);
    return ad < 1.0f ? 0.5f * d * d : ad - 0.5f;
}

#define FGKEY 0x007FFFFFu   // f2key(-INFINITY); pads use 0u; real losses >= f2key(0)=0x80000000

// ---------- kernel 1: per-anchor CE (exp2-based LSE), block-level fg partials, no atomics ----------
__global__ __launch_bounds__(256) void cls_kernel(
        const float* __restrict__ cls_logits,      // [B,A,C]
        const int*   __restrict__ matched_idxs,    // [B,A]
        const int*   __restrict__ labels,          // [B,G]
        const float* __restrict__ boxes,           // [B,G,4]
        const float* __restrict__ anchors,         // [B,A,4]
        const float* __restrict__ bbox_regression, // [B,A,4]
        float* __restrict__ neg_loss,              // [B,A] out (-inf marks fg)
        float* __restrict__ part_cls,              // [B,CLS_BLOCKS] out
        float* __restrict__ part_box) {            // [B,CLS_BLOCKS] out
    __shared__ float shc[4], shb[4];
    int b   = blockIdx.y;
    int grp = threadIdx.x >> 4;
    int sub = threadIdx.x & 15;
    int a   = blockIdx.x * APB + grp;
    bool valid = (a < An);
    size_t row = (size_t)b * An + a;

    float my_cl = 0.f, my_box = 0.f;
    if (valid) {
        const float* lg = cls_logits + row * (size_t)Cn;
        // 201 elements over 16 lanes: sub + 16j, j = 0..12 (j=12 only for sub<9)
        float v[13];
        #pragma unroll
        for (int j = 0; j < 12; ++j) v[j] = lg[sub + 16 * j];
        v[12] = (sub < Cn - 192) ? lg[sub + 192] : -INFINITY;

        float mx = v[0];
        #pragma unroll
        for (int j = 1; j < 13; ++j) mx = fmaxf(mx, v[j]);
        #pragma unroll
        for (int off = 8; off; off >>= 1) mx = fmaxf(mx, __shfl_xor(mx, off, 64));

        // exp2-based: one v_exp_f32 per element (exp2f(-inf) = 0 handles the tail lane)
        float s = 0.f;
        #pragma unroll
        for (int j = 0; j < 13; ++j) s += exp2f((v[j] - mx) * LOG2E);
        #pragma unroll
        for (int off = 8; off; off >>= 1) s += __shfl_xor(s, off, 64);

        if (sub == 0) {
            float lse = mx + logf(s);
            int   mi  = matched_idxs[row];
            bool  fg  = (mi >= 0);
            int   t   = fg ? labels[b * Gn + mi] : 0;
            float cl  = lse - lg[t];
            if (fg) {
                neg_loss[row] = -INFINITY;
                my_cl = cl;
                const float* gt = boxes           + (size_t)(b * Gn + mi) * 4;
                const float* an = anchors         + row * 4;
                const float* rg = bbox_regression + row * 4;
                float aw  = an[2] - an[0], ah  = an[3] - an[1];
                float acx = an[0] + 0.5f * aw, acy = an[1] + 0.5f * ah;
                float gw  = gt[2] - gt[0], gh  = gt[3] - gt[1];
                float gcx = gt[0] + 0.5f * gw, gcy = gt[1] + 0.5f * gh;
                float t0 = 10.f * (gcx - acx) / aw;
                float t1 = 10.f * (gcy - acy) / ah;
                float t2 = 5.f * logf(gw / aw);
                float t3 = 5.f * logf(gh / ah);
                my_box = smooth_l1(rg[0] - t0) + smooth_l1(rg[1] - t1)
                       + smooth_l1(rg[2] - t2) + smooth_l1(rg[3] - t3);
            } else {
                neg_loss[row] = cl;
            }
        }
    }
    // block-reduce fg partials (nonzero only at sub==0 lanes: 0,16,32,48 of each wave)
    my_cl  += __shfl_xor(my_cl, 16, 64);  my_cl  += __shfl_xor(my_cl, 32, 64);
    my_box += __shfl_xor(my_box, 16, 64); my_box += __shfl_xor(my_box, 32, 64);
    int wv = threadIdx.x >> 6, lane = threadIdx.x & 63;
    if (lane == 0) { shc[wv] = my_cl; shb[wv] = my_box; }
    __syncthreads();
    if (threadIdx.x == 0) {
        part_cls[b * CLS_BLOCKS + blockIdx.x] = shc[0] + shc[1] + shc[2] + shc[3];
        part_box[b * CLS_BLOCKS + blockIdx.x] = shb[0] + shb[1] + shb[2] + shb[3];
    }
}

// ---------- kernel 2: per-batch fg totals + exact top-k sum via 4-pass radix-256 select ----------
#define MIT 9   // ceil(8732 / 1024) elements per thread
__global__ __launch_bounds__(1024) void mining_kernel(
        const float* __restrict__ neg_loss,   // [B,A]
        const float* __restrict__ part_cls,   // [B,CLS_BLOCKS]
        const float* __restrict__ part_box,   // [B,CLS_BLOCKS]
        int*   __restrict__ fg_count,         // [B] out
        float* __restrict__ fg_cls_sum,       // [B] out
        float* __restrict__ bbox_sum,         // [B] out
        float* __restrict__ topk_batch) {     // [B] out
    int b    = blockIdx.x;
    int tid  = threadIdx.x;
    int lane = tid & 63;
    int wv   = tid >> 6;
    __shared__ int   h[256];
    __shared__ float wfa[16], wfb[16];
    __shared__ int   wia[16];
    __shared__ unsigned int sh_prefix;
    __shared__ int sh_krem, sh_k;

    // load this thread's keys once (order-preserving uint); count fg sentinels for free
    const float* vals = neg_loss + (size_t)b * An;
    unsigned int key[MIT];
    int myfg = 0;
    #pragma unroll
    for (int j = 0; j < MIT; ++j) {
        int i = tid + j * 1024;
        unsigned int kk = 0u;
        if (i < An) { kk = f2key(vals[i]); myfg += (kk == FGKEY); }
        key[j] = kk;
    }
    float mc = (tid < CLS_BLOCKS) ? part_cls[b * CLS_BLOCKS + tid] : 0.f;
    float mb = (tid < CLS_BLOCKS) ? part_box[b * CLS_BLOCKS + tid] : 0.f;
    #pragma unroll
    for (int off = 32; off; off >>= 1) {
        mc   += __shfl_xor(mc, off, 64);
        mb   += __shfl_xor(mb, off, 64);
        myfg += __shfl_xor(myfg, off, 64);
    }
    if (lane == 0) { wfa[wv] = mc; wfb[wv] = mb; wia[wv] = myfg; }
    if (tid < 256) h[tid] = 0;
    __syncthreads();
    if (tid == 0) {
        float cs = 0.f, bs = 0.f; int fc = 0;
        for (int i = 0; i < 16; ++i) { cs += wfa[i]; bs += wfb[i]; fc += wia[i]; }
        fg_count[b] = fc; fg_cls_sum[b] = cs; bbox_sum[b] = bs;
        int k = 3 * fc, nneg = An - fc;
        if (k > nneg) k = nneg;
        sh_k = k; sh_krem = k; sh_prefix = 0u;
    }
    __syncthreads();
    int k = sh_k;
    if (k <= 0) { if (tid == 0) topk_batch[b] = 0.f; return; }

    // MSB-first radix-256: T = k-th largest key. fg(-inf)/pad keys < f2key(0) <= any real loss,
    // and k <= #negatives guarantees T is a real bg loss.
    unsigned int prefix = 0; int krem = k;
    for (int p = 0; p < 4; ++p) {
        int shift = 24 - 8 * p;
        #pragma unroll
        for (int j = 0; j < MIT; ++j) {
            unsigned int u = key[j];
            bool match = (p == 0) || ((u >> (shift + 8)) == prefix);
            if (match) atomicAdd(&h[(u >> shift) & 255], 1);
        }
        __syncthreads();
        if (wv == 0) {
            // lane l owns bins [252-4l .. 255-4l]; inclusive shfl scan = count(byte >= 252-4l)
            int b0 = 252 - 4 * lane;
            int c0 = h[b0], c1 = h[b0 + 1], c2 = h[b0 + 2], c3 = h[b0 + 3];
            int local = c0 + c1 + c2 + c3;
            int inc = local;
            #pragma unroll
            for (int off = 1; off < 64; off <<= 1) {
                int n = __shfl_up(inc, off, 64);
                if (lane >= off) inc += n;
            }
            unsigned long long m = __ballot(inc >= krem);
            int sel = __ffsll(m) - 1;
            if (lane == sel) {
                int prev = inc - local;  // count with byte > b0+3
                int digit, above;
                if      (prev + c3 >= krem)           { digit = b0 + 3; above = prev; }
                else if (prev + c3 + c2 >= krem)      { digit = b0 + 2; above = prev + c3; }
                else if (prev + c3 + c2 + c1 >= krem) { digit = b0 + 1; above = prev + c3 + c2; }
                else                                  { digit = b0;     above = prev + c3 + c2 + c1; }
                sh_prefix = (prefix << 8) | (unsigned int)digit;
                sh_krem   = krem - above;
            }
        }
        __syncthreads();
        prefix = sh_prefix; krem = sh_krem;
        if (p < 3) {
            if (tid < 256) h[tid] = 0;
            __syncthreads();
        }
    }

    // exact sum: strictly-greater elements + tie correction at the threshold
    unsigned int T = prefix;
    float fs = 0.f; int cgt = 0;
    #pragma unroll
    for (int j = 0; j < MIT; ++j)
        if (key[j] > T) { fs += key2f(key[j]); cgt++; }
    #pragma unroll
    for (int off = 32; off; off >>= 1) {
        fs  += __shfl_xor(fs,  off, 64);
        cgt += __shfl_xor(cgt, off, 64);
    }
    if (lane == 0) { wfa[wv] = fs; wia[wv] = cgt; }
    __syncthreads();
    if (tid == 0) {
        float s = 0.f; int c = 0;
        for (int i = 0; i < 16; ++i) { s += wfa[i]; c += wia[i]; }
        topk_batch[b] = s + (float)(k - c) * key2f(T);
    }
}

// ---------- kernel 3: finalize (one wave) ----------
__global__ void finalize_kernel(
        const int*   __restrict__ fg_count,
        const float* __restrict__ fg_cls_sum,
        const float* __restrict__ bbox_sum,
        const float* __restrict__ topk_batch,
        const float* __restrict__ rejection_logits,  // [B,2]
        const int*   __restrict__ image_label,       // [B]
        float* __restrict__ out) {
    int lane = threadIdx.x;
    int   fc = (lane < Bn) ? fg_count[lane]   : 0;
    float tk = (lane < Bn) ? topk_batch[lane] : 0.f;
    float cs = (lane < Bn) ? fg_cls_sum[lane] : 0.f;
    float bs = (lane < Bn) ? bbox_sum[lane]   : 0.f;
    float vl = 0.f;
    if (lane < Bn) {
        float r0 = rejection_logits[lane * 2];
        float r1 = rejection_logits[lane * 2 + 1];
        float m  = fmaxf(r0, r1);
        float lse = m + logf(expf(r0 - m) + expf(r1 - m));
        vl = lse - ((image_label[lane] == 0) ? r0 : r1);
    }
    #pragma unroll
    for (int off = 32; off; off >>= 1) {
        fc += __shfl_xor(fc, off, 64);
        tk += __shfl_xor(tk, off, 64);
        cs += __shfl_xor(cs, off, 64);
        bs += __shfl_xor(bs, off, 64);
        vl += __shfl_xor(vl, off, 64);
    }
    if (lane == 0) {
        float N   = (float)((fc > 1) ? fc : 1);
        float reg = bs / N;
        float cls = (cs + tk) / N;   // N_neg = 0 (MIN_NEG_SAMPLES = 0)
        float val = vl / (float)Bn;
        float loss = 0.5f * (reg + cls) + 0.5f * val;
        out[0] = loss; out[1] = reg; out[2] = cls; out[3] = val;
    }
}

extern "C" void kernel_launch(void* const* d_in, const int* in_sizes, int n_in,
                              void* d_out, int out_size, void* d_ws, size_t ws_size,
                              hipStream_t stream) {
    const float* boxes            = (const float*)d_in[0];
    const int*   labels           = (const int*)  d_in[1];
    const int*   image_label      = (const int*)  d_in[2];
    const float* bbox_regression  = (const float*)d_in[3];
    const float* cls_logits       = (const float*)d_in[4];
    const float* rejection_logits = (const float*)d_in[5];
    const float* anchors          = (const float*)d_in[6];
    const int*   matched_idxs     = (const int*)  d_in[7];
    float* out = (float*)d_out;

    // workspace layout (everything fully rewritten each call; ws is poison-safe)
    float* neg_loss   = (float*)d_ws;                          // B*A floats
    float* part_cls   = neg_loss + (size_t)Bn * An;            // B*CLS_BLOCKS
    float* part_box   = part_cls + Bn * CLS_BLOCKS;            // B*CLS_BLOCKS
    int*   fg_count   = (int*)(part_box + Bn * CLS_BLOCKS);    // B
    float* fg_cls_sum = (float*)(fg_count + Bn);               // B
    float* bbox_sum   = fg_cls_sum + Bn;                       // B
    float* topk_batch = bbox_sum + Bn;                         // B

    dim3 grid(CLS_BLOCKS, Bn);
    cls_kernel<<<grid, 256, 0, stream>>>(cls_logits, matched_idxs, labels,
                                         boxes, anchors, bbox_regression,
                                         neg_loss, part_cls, part_box);

    mining_kernel<<<Bn, 1024, 0, stream>>>(neg_loss, part_cls, part_box,
                                           fg_count, fg_cls_sum, bbox_sum, topk_batch);

    finalize_kernel<<<1, 64, 0, stream>>>(fg_count, fg_cls_sum, bbox_sum, topk_batch,
                                          rejection_logits, image_label, out);
}

// Round 2
// 327.636 us; speedup vs baseline: 1.0672x; 1.0208x over previous
//
#include <hip/hip_runtime.h>
#include <math.h>

#define Bn 32
#define An 8732
#define Cn 201
#define Gn 50

#define APB 16                      // anchors per block in cls kernel (16 lanes/anchor, 256 thr)
#define CLS_BLOCKS ((An + APB - 1) / APB)   // 546 blocks per batch
#define LOG2E 1.44269504088896340736f

// ---------- helpers ----------
__device__ __forceinline__ unsigned int f2key(float f) {
    unsigned int u = __float_as_uint(f);
    return (u & 0x80000000u) ? ~u : (u | 0x80000000u);
}
__device__ __forceinline__ float key2f(unsigned int k) {
    return (k & 0x80000000u) ? __uint_as_float(k & 0x7FFFFFFFu) : __uint_as_float(~k);
}
__device__ __forceinline__ float smooth_l1(float d) {
    float ad = fabsf(d);
    return ad < 1.0f ? 0.5f * d * d : ad - 0.5f;
}

#define FGKEY 0x007FFFFFu   // f2key(-INFINITY); pads use 0u; real losses >= f2key(0)=0x80000000

// ---------- kernel 1: per-anchor CE (exp2-based LSE), block-level fg partials, no atomics ----------
__global__ __launch_bounds__(256) void cls_kernel(
        const float* __restrict__ cls_logits,      // [B,A,C]
        const int*   __restrict__ matched_idxs,    // [B,A]
        const int*   __restrict__ labels,          // [B,G]
        const float* __restrict__ boxes,           // [B,G,4]
        const float* __restrict__ anchors,         // [B,A,4]
        const float* __restrict__ bbox_regression, // [B,A,4]
        float* __restrict__ neg_loss,              // [B,A] out (-inf marks fg)
        float* __restrict__ part_cls,              // [B,CLS_BLOCKS] out
        float* __restrict__ part_box,              // [B,CLS_BLOCKS] out
        int*   __restrict__ done_counter) {        // [1] zeroed here for mining's fused finalize
    __shared__ float shc[4], shb[4];
    int b   = blockIdx.y;
    int grp = threadIdx.x >> 4;
    int sub = threadIdx.x & 15;
    int a   = blockIdx.x * APB + grp;
    bool valid = (a < An);
    size_t row = (size_t)b * An + a;

    if (blockIdx.x == 0 && b == 0 && threadIdx.x == 0)
        *done_counter = 0;   // visible to mining via kernel boundary

    float my_cl = 0.f, my_box = 0.f;
    if (valid) {
        const float* lg = cls_logits + row * (size_t)Cn;
        // 201 elements over 16 lanes: sub + 16j, j = 0..12 (j=12 only for sub<9)
        float v[13];
        #pragma unroll
        for (int j = 0; j < 12; ++j) v[j] = lg[sub + 16 * j];
        v[12] = (sub < Cn - 192) ? lg[sub + 192] : -INFINITY;

        float mx = v[0];
        #pragma unroll
        for (int j = 1; j < 13; ++j) mx = fmaxf(mx, v[j]);
        #pragma unroll
        for (int off = 8; off; off >>= 1) mx = fmaxf(mx, __shfl_xor(mx, off, 64));

        // exp2-based: one v_exp_f32 per element (exp2f(-inf) = 0 handles the tail lane)
        float s = 0.f;
        #pragma unroll
        for (int j = 0; j < 13; ++j) s += exp2f((v[j] - mx) * LOG2E);
        #pragma unroll
        for (int off = 8; off; off >>= 1) s += __shfl_xor(s, off, 64);

        if (sub == 0) {
            float lse = mx + logf(s);
            int   mi  = matched_idxs[row];
            bool  fg  = (mi >= 0);
            // bg target is class 0 -> logit lg[0] == v[0] of this lane (sub==0): no reload
            float cl  = lse - (fg ? lg[labels[b * Gn + mi]] : v[0]);
            if (fg) {
                neg_loss[row] = -INFINITY;
                my_cl = cl;
                const float* gt = boxes           + (size_t)(b * Gn + mi) * 4;
                const float* an = anchors         + row * 4;
                const float* rg = bbox_regression + row * 4;
                float aw  = an[2] - an[0], ah  = an[3] - an[1];
                float acx = an[0] + 0.5f * aw, acy = an[1] + 0.5f * ah;
                float gw  = gt[2] - gt[0], gh  = gt[3] - gt[1];
                float gcx = gt[0] + 0.5f * gw, gcy = gt[1] + 0.5f * gh;
                float t0 = 10.f * (gcx - acx) / aw;
                float t1 = 10.f * (gcy - acy) / ah;
                float t2 = 5.f * logf(gw / aw);
                float t3 = 5.f * logf(gh / ah);
                my_box = smooth_l1(rg[0] - t0) + smooth_l1(rg[1] - t1)
                       + smooth_l1(rg[2] - t2) + smooth_l1(rg[3] - t3);
            } else {
                neg_loss[row] = cl;
            }
        }
    }
    // block-reduce fg partials (nonzero only at sub==0 lanes: 0,16,32,48 of each wave)
    my_cl  += __shfl_xor(my_cl, 16, 64);  my_cl  += __shfl_xor(my_cl, 32, 64);
    my_box += __shfl_xor(my_box, 16, 64); my_box += __shfl_xor(my_box, 32, 64);
    int wv = threadIdx.x >> 6, lane = threadIdx.x & 63;
    if (lane == 0) { shc[wv] = my_cl; shb[wv] = my_box; }
    __syncthreads();
    if (threadIdx.x == 0) {
        part_cls[b * CLS_BLOCKS + blockIdx.x] = shc[0] + shc[1] + shc[2] + shc[3];
        part_box[b * CLS_BLOCKS + blockIdx.x] = shb[0] + shb[1] + shb[2] + shb[3];
    }
}

// ---------- kernel 2: fg totals + top-k sum (radix-256, per-wave privatized hist) + fused finalize ----------
#define MIT 9       // ceil(8732 / 1024) elements per thread
#define HPAD 260    // per-wave hist stride (words): staggers banks across waves (2-way, free)
__global__ __launch_bounds__(1024) void mining_kernel(
        const float* __restrict__ neg_loss,   // [B,A]
        const float* __restrict__ part_cls,   // [B,CLS_BLOCKS]
        const float* __restrict__ part_box,   // [B,CLS_BLOCKS]
        int*   __restrict__ fg_count,         // [B]
        float* __restrict__ fg_cls_sum,       // [B]
        float* __restrict__ bbox_sum,         // [B]
        float* __restrict__ topk_batch,       // [B]
        int*   __restrict__ done_counter,     // [1], pre-zeroed by cls_kernel
        const float* __restrict__ rejection_logits,  // [B,2]
        const int*   __restrict__ image_label,       // [B]
        float* __restrict__ out) {                   // [4]
    int b    = blockIdx.x;
    int tid  = threadIdx.x;
    int lane = tid & 63;
    int wv   = tid >> 6;
    __shared__ int   priv[16 * HPAD];   // per-wave histograms
    __shared__ int   comb[256];
    __shared__ float wfa[16], wfb[16];
    __shared__ int   wia[16];
    __shared__ unsigned int sh_prefix;
    __shared__ int sh_krem, sh_k, sh_last;

    // load this thread's keys once (order-preserving uint); count fg sentinels for free
    const float* vals = neg_loss + (size_t)b * An;
    unsigned int key[MIT];
    int myfg = 0;
    #pragma unroll
    for (int j = 0; j < MIT; ++j) {
        int i = tid + j * 1024;
        unsigned int kk = 0u;
        if (i < An) { kk = f2key(vals[i]); myfg += (kk == FGKEY); }
        key[j] = kk;
    }
    float mc = (tid < CLS_BLOCKS) ? part_cls[b * CLS_BLOCKS + tid] : 0.f;
    float mb = (tid < CLS_BLOCKS) ? part_box[b * CLS_BLOCKS + tid] : 0.f;
    #pragma unroll
    for (int off = 32; off; off >>= 1) {
        mc   += __shfl_xor(mc, off, 64);
        mb   += __shfl_xor(mb, off, 64);
        myfg += __shfl_xor(myfg, off, 64);
    }
    if (lane == 0) { wfa[wv] = mc; wfb[wv] = mb; wia[wv] = myfg; }
    // clear private histograms (4160 words over 1024 threads)
    for (int i = tid; i < 16 * HPAD; i += 1024) priv[i] = 0;
    __syncthreads();
    if (tid == 0) {
        float cs = 0.f, bs = 0.f; int fc = 0;
        for (int i = 0; i < 16; ++i) { cs += wfa[i]; bs += wfb[i]; fc += wia[i]; }
        __hip_atomic_store(&fg_count[b],   fc, __ATOMIC_RELAXED, __HIP_MEMORY_SCOPE_AGENT);
        __hip_atomic_store(&fg_cls_sum[b], cs, __ATOMIC_RELAXED, __HIP_MEMORY_SCOPE_AGENT);
        __hip_atomic_store(&bbox_sum[b],   bs, __ATOMIC_RELAXED, __HIP_MEMORY_SCOPE_AGENT);
        int k = 3 * fc, nneg = An - fc;
        if (k > nneg) k = nneg;
        sh_k = k;
    }
    __syncthreads();
    int k = sh_k;
    float result = 0.f;

    if (k > 0) {
        // MSB-first radix-256: T = k-th largest key. fg(-inf)/pad keys < f2key(0) <= any real
        // loss, and k <= #negatives guarantees T is a real bg loss. Histograms are per-wave
        // privatized: CE losses cluster into few bins, and 1024-thread same-address LDS atomics
        // serialize; per-wave cuts worst-case contention 16x and waves proceed in parallel.
        unsigned int prefix = 0; int krem = k;
        for (int p = 0; p < 4; ++p) {
            int shift = 24 - 8 * p;
            int* ph = &priv[wv * HPAD];
            #pragma unroll
            for (int j = 0; j < MIT; ++j) {
                unsigned int u = key[j];
                bool match = (p == 0) || ((u >> (shift + 8)) == prefix);
                if (match) atomicAdd(&ph[(u >> shift) & 255], 1);
            }
            __syncthreads();
            // combine 16 wave-histograms; fold the clear for the next pass into the same sweep
            if (tid < 256) {
                int s = 0;
                #pragma unroll
                for (int w = 0; w < 16; ++w) { s += priv[w * HPAD + tid]; priv[w * HPAD + tid] = 0; }
                comb[tid] = s;
            }
            __syncthreads();
            if (wv == 0) {
                // lane l owns bins [252-4l .. 255-4l]; inclusive shfl scan = count(byte >= 252-4l)
                int b0 = 252 - 4 * lane;
                int c0 = comb[b0], c1 = comb[b0 + 1], c2 = comb[b0 + 2], c3 = comb[b0 + 3];
                int local = c0 + c1 + c2 + c3;
                int inc = local;
                #pragma unroll
                for (int off = 1; off < 64; off <<= 1) {
                    int n = __shfl_up(inc, off, 64);
                    if (lane >= off) inc += n;
                }
                unsigned long long m = __ballot(inc >= krem);
                int sel = __ffsll(m) - 1;
                if (lane == sel) {
                    int prev = inc - local;  // count with byte > b0+3
                    int digit, above;
                    if      (prev + c3 >= krem)           { digit = b0 + 3; above = prev; }
                    else if (prev + c3 + c2 >= krem)      { digit = b0 + 2; above = prev + c3; }
                    else if (prev + c3 + c2 + c1 >= krem) { digit = b0 + 1; above = prev + c3 + c2; }
                    else                                  { digit = b0;     above = prev + c3 + c2 + c1; }
                    sh_prefix = (prefix << 8) | (unsigned int)digit;
                    sh_krem   = krem - above;
                }
            }
            __syncthreads();
            prefix = sh_prefix; krem = sh_krem;
        }

        // exact sum: strictly-greater elements + tie correction at the threshold
        unsigned int T = prefix;
        float fs = 0.f; int cgt = 0;
        #pragma unroll
        for (int j = 0; j < MIT; ++j)
            if (key[j] > T) { fs += key2f(key[j]); cgt++; }
        #pragma unroll
        for (int off = 32; off; off >>= 1) {
            fs  += __shfl_xor(fs,  off, 64);
            cgt += __shfl_xor(cgt, off, 64);
        }
        if (lane == 0) { wfa[wv] = fs; wia[wv] = cgt; }
        __syncthreads();
        if (tid == 0) {
            float s = 0.f; int c = 0;
            for (int i = 0; i < 16; ++i) { s += wfa[i]; c += wia[i]; }
            result = s + (float)(k - c) * key2f(T);
        }
    }

    // publish this batch's top-k and elect the finalizing block (device-scope protocol:
    // relaxed agent stores ordered by the acq_rel fetch_add; readers use agent atomic loads
    // so no stale per-XCD L2 lines are observed)
    if (tid == 0) {
        __hip_atomic_store(&topk_batch[b], result, __ATOMIC_RELAXED, __HIP_MEMORY_SCOPE_AGENT);
        int old = __hip_atomic_fetch_add(done_counter, 1, __ATOMIC_ACQ_REL, __HIP_MEMORY_SCOPE_AGENT);
        sh_last = (old == Bn - 1);
    }
    __syncthreads();
    if (sh_last && tid < 64) {
        int l = tid;
        int   fc = 0; float tk = 0.f, cs = 0.f, bs = 0.f, vl = 0.f;
        if (l < Bn) {
            fc = __hip_atomic_load(&fg_count[l],   __ATOMIC_RELAXED, __HIP_MEMORY_SCOPE_AGENT);
            tk = __hip_atomic_load(&topk_batch[l], __ATOMIC_RELAXED, __HIP_MEMORY_SCOPE_AGENT);
            cs = __hip_atomic_load(&fg_cls_sum[l], __ATOMIC_RELAXED, __HIP_MEMORY_SCOPE_AGENT);
            bs = __hip_atomic_load(&bbox_sum[l],   __ATOMIC_RELAXED, __HIP_MEMORY_SCOPE_AGENT);
            float r0 = rejection_logits[l * 2];
            float r1 = rejection_logits[l * 2 + 1];
            float m  = fmaxf(r0, r1);
            float lse = m + logf(expf(r0 - m) + expf(r1 - m));
            vl = lse - ((image_label[l] == 0) ? r0 : r1);
        }
        #pragma unroll
        for (int off = 32; off; off >>= 1) {
            fc += __shfl_xor(fc, off, 64);
            tk += __shfl_xor(tk, off, 64);
            cs += __shfl_xor(cs, off, 64);
            bs += __shfl_xor(bs, off, 64);
            vl += __shfl_xor(vl, off, 64);
        }
        if (l == 0) {
            float N   = (float)((fc > 1) ? fc : 1);
            float reg = bs / N;
            float cls = (cs + tk) / N;   // N_neg = 0 (MIN_NEG_SAMPLES = 0)
            float val = vl / (float)Bn;
            out[0] = 0.5f * (reg + cls) + 0.5f * val;
            out[1] = reg; out[2] = cls; out[3] = val;
        }
    }
}

extern "C" void kernel_launch(void* const* d_in, const int* in_sizes, int n_in,
                              void* d_out, int out_size, void* d_ws, size_t ws_size,
                              hipStream_t stream) {
    const float* boxes            = (const float*)d_in[0];
    const int*   labels           = (const int*)  d_in[1];
    const int*   image_label      = (const int*)  d_in[2];
    const float* bbox_regression  = (const float*)d_in[3];
    const float* cls_logits       = (const float*)d_in[4];
    const float* rejection_logits = (const float*)d_in[5];
    const float* anchors          = (const float*)d_in[6];
    const int*   matched_idxs     = (const int*)  d_in[7];
    float* out = (float*)d_out;

    // workspace layout (everything read is written earlier in the same call; ws is poison-safe)
    float* neg_loss   = (float*)d_ws;                          // B*A floats
    float* part_cls   = neg_loss + (size_t)Bn * An;            // B*CLS_BLOCKS
    float* part_box   = part_cls + Bn * CLS_BLOCKS;            // B*CLS_BLOCKS
    int*   fg_count   = (int*)(part_box + Bn * CLS_BLOCKS);    // B
    float* fg_cls_sum = (float*)(fg_count + Bn);               // B
    float* bbox_sum   = fg_cls_sum + Bn;                       // B
    float* topk_batch = bbox_sum + Bn;                         // B
    int*   done_ctr   = (int*)(topk_batch + Bn);               // 1

    dim3 grid(CLS_BLOCKS, Bn);
    cls_kernel<<<grid, 256, 0, stream>>>(cls_logits, matched_idxs, labels,
                                         boxes, anchors, bbox_regression,
                                         neg_loss, part_cls, part_box, done_ctr);

    mining_kernel<<<Bn, 1024, 0, stream>>>(neg_loss, part_cls, part_box,
                                           fg_count, fg_cls_sum, bbox_sum, topk_batch,
                                           done_ctr, rejection_logits, image_label, out);
}